// Round 6
// baseline (621.747 us; speedup 1.0000x reference)
//
#include <hip/hip_runtime.h>

#define BB 4
#define CC 64
#define SS 2
#define HCC 32
#define AREA_ 16384
#define KDIM 288

typedef _Float16 half8 __attribute__((ext_vector_type(8)));
typedef float f32x16 __attribute__((ext_vector_type(16)));

static __device__ __forceinline__ float warp_rsum(float v){
#pragma unroll
  for (int o=32;o>0;o>>=1) v += __shfl_down(v,o,64);
  return v;
}
static __device__ __forceinline__ float warp_rmax(float v){
#pragma unroll
  for (int o=32;o>0;o>>=1) v = fmaxf(v,__shfl_down(v,o,64));
  return v;
}

// ---------- 64x64 1x1 conv ----------
__global__ __launch_bounds__(256) void conv64_kernel(const float* __restrict__ in,
    const float* __restrict__ wmat, float* __restrict__ out){
  int b = blockIdx.x >> 7;
  int p0 = (blockIdx.x & 127) << 7;
  __shared__ float tile[64][132];
  __shared__ float wsm[64][68];
  for (int idx = threadIdx.x; idx < 4096; idx += 256){
    int c = idx & 63, o = idx >> 6;
    wsm[c][o] = wmat[o*64 + c];
  }
  const float* inb = in + (size_t)b*CC*AREA_ + p0;
  for (int idx = threadIdx.x; idx < 8192; idx += 256){
    int c = idx >> 7, pp = idx & 127;
    tile[c][pp] = inb[(size_t)c*AREA_ + pp];
  }
  __syncthreads();
  int px = (threadIdx.x & 31) * 4;
  int og = threadIdx.x >> 5;
  float4 acc[8];
#pragma unroll
  for (int i=0;i<8;i++) acc[i] = make_float4(0.f,0.f,0.f,0.f);
  for (int c=0;c<64;c++){
    float4 v  = *(const float4*)&tile[c][px];
    float4 w0 = *(const float4*)&wsm[c][og*8];
    float4 w1 = *(const float4*)&wsm[c][og*8+4];
    float wv[8] = {w0.x,w0.y,w0.z,w0.w,w1.x,w1.y,w1.z,w1.w};
#pragma unroll
    for (int i=0;i<8;i++){
      acc[i].x = fmaf(wv[i], v.x, acc[i].x);
      acc[i].y = fmaf(wv[i], v.y, acc[i].y);
      acc[i].z = fmaf(wv[i], v.z, acc[i].z);
      acc[i].w = fmaf(wv[i], v.w, acc[i].w);
    }
  }
  float* ob = out + (size_t)b*CC*AREA_ + p0 + px;
#pragma unroll
  for (int i=0;i<8;i++)
    *(float4*)&ob[(size_t)(og*8+i)*AREA_] = acc[i];
}

// ---------- BN ----------
__global__ __launch_bounds__(256) void bn_part_kernel(const float* __restrict__ src,
    float* __restrict__ part){
  int c = blockIdx.x, chunk = blockIdx.y;
  float s1=0.f, s2=0.f;
  for (int b=0;b<BB;b++){
    const float* p = src + ((size_t)b*CC + c)*AREA_ + chunk*2048;
    for (int i=threadIdx.x;i<2048;i+=256){ float v=p[i]; s1+=v; s2+=v*v; }
  }
  __shared__ float red[8];
  float w1 = warp_rsum(s1), w2 = warp_rsum(s2);
  int lane = threadIdx.x & 63, wid = threadIdx.x >> 6;
  if (lane==0){ red[wid]=w1; red[4+wid]=w2; }
  __syncthreads();
  if (threadIdx.x==0){
    atomicAdd(&part[c], red[0]+red[1]+red[2]+red[3]);
    atomicAdd(&part[64+c], red[4]+red[5]+red[6]+red[7]);
  }
}

__global__ void bn_fin_kernel(const float* __restrict__ part, const float* __restrict__ gam,
    const float* __restrict__ bet, float* __restrict__ sb){
  int c = threadIdx.x;
  const float N = (float)(BB*AREA_);
  float m = part[c]/N;
  float var = part[64+c]/N - m*m;
  float sc = gam[c]*rsqrtf(var + 1e-5f);
  sb[c] = sc;
  sb[64+c] = bet[c] - m*sc;
}

__global__ __launch_bounds__(256) void bn_apply_relu_kernel(const float* __restrict__ src,
    const float* __restrict__ sb, float* __restrict__ dst){
  size_t i = (size_t)blockIdx.x*256 + threadIdx.x;
  int c = (int)((i >> 14) & 63);
  float v = fmaf(src[i], sb[c], sb[64+c]);
  dst[i] = v > 0.f ? v : 0.f;
}

// ---------- query conv ----------
__global__ __launch_bounds__(256) void qq_kernel(const float* __restrict__ y,
    const float* __restrict__ qw, float* __restrict__ qq){
  int blk = blockIdx.x;
  int p0 = (blk & 127) << 7;
  int s = (blk >> 7) & 1;
  int b = blk >> 8;
  __shared__ float tile[32][132];
  __shared__ float wsm[32][36];
  const float* qws = qw + s*HCC*HCC;
  for (int idx=threadIdx.x; idx<1024; idx+=256){
    int c = idx & 31, o = idx >> 5;
    wsm[c][o] = qws[o*32 + c];
  }
  const float* yb = y + ((size_t)b*CC + s*HCC)*AREA_ + p0;
  for (int idx=threadIdx.x; idx<4096; idx+=256){
    int c=idx>>7, pp=idx&127;
    tile[c][pp] = yb[(size_t)c*AREA_ + pp];
  }
  __syncthreads();
  int px = (threadIdx.x & 31) * 4;
  int og = threadIdx.x >> 5;
  float4 acc[4];
#pragma unroll
  for (int i=0;i<4;i++) acc[i] = make_float4(0.f,0.f,0.f,0.f);
  for (int c=0;c<32;c++){
    float4 v  = *(const float4*)&tile[c][px];
    float4 w0 = *(const float4*)&wsm[c][og*4];
    float wv[4] = {w0.x,w0.y,w0.z,w0.w};
#pragma unroll
    for (int i=0;i<4;i++){
      acc[i].x = fmaf(wv[i], v.x, acc[i].x);
      acc[i].y = fmaf(wv[i], v.y, acc[i].y);
      acc[i].z = fmaf(wv[i], v.z, acc[i].z);
      acc[i].w = fmaf(wv[i], v.w, acc[i].w);
    }
  }
  float* ob = qq + ((size_t)(b*SS+s)*HCC)*AREA_ + p0 + px;
#pragma unroll
  for (int i=0;i<4;i++)
    *(float4*)&ob[(size_t)(og*4+i)*AREA_] = acc[i];
}

// ---------- U fragment, computed directly in registers (no LDS) ----------
// Returns fp16 of U[g][k0+8u .. +8] where h0u = (k0&127) + 8u, w = k0>>7.
__device__ __forceinline__ half8 ufrag(const float* __restrict__ yb,
    const float* __restrict__ qqb, int g, int w, int h0u, int dil){
  float v[8];
  if (g < 256){
    int l = g >> 5, ch = g & 31;
    int oy = ((0x6A40 >> (2*l)) & 3) - 1;
    int ox = ((0x6A4  >> (2*l)) & 3) - 1;
    const float* crow = yb + (size_t)ch*AREA_ + w*128 + h0u;
    float4 c0 = *(const float4*)crow;
    float4 c1 = *(const float4*)(crow+4);
    float cen[8] = {c0.x,c0.y,c0.z,c0.w,c1.x,c1.y,c1.z,c1.w};
    float nb[8];
    int wy = w + oy*dil;
    if (wy >= 0 && wy < 128){
      int oxd = ox*dil;
      const float* nrow = yb + (size_t)ch*AREA_ + wy*128 + h0u + oxd;
      float nn[8];
      __builtin_memcpy(nn, nrow, 32);
      int hbase = h0u + oxd;
#pragma unroll
      for (int j=0;j<8;j++){
        int hx = hbase + j;
        nb[j] = (hx>=0 && hx<128) ? nn[j] : 0.f;
      }
    } else {
#pragma unroll
      for (int j=0;j<8;j++) nb[j]=0.f;
    }
#pragma unroll
    for (int j=0;j<8;j++) v[j] = cen[j]-nb[j];
  } else {
    const float* src = (g < 288) ? (yb + (size_t)(g-256)*AREA_) : (qqb + (size_t)(g-288)*AREA_);
    const float* crow = src + w*128 + h0u;
    float4 c0 = *(const float4*)crow;
    float4 c1 = *(const float4*)(crow+4);
    v[0]=c0.x; v[1]=c0.y; v[2]=c0.z; v[3]=c0.w; v[4]=c1.x; v[5]=c1.y; v[6]=c1.z; v[7]=c1.w;
  }
  half8 hv;
#pragma unroll
  for (int j=0;j<8;j++) hv[j] = (_Float16)v[j];
  return hv;
}

// ---------- MFMA gram, register-direct (no LDS, no barriers) ----------
// Linear grid 544: bs = blk&7 (XCD-pins each bs's y/qq into one L2), slot = blk>>3.
__global__ __launch_bounds__(256,2) void gram_kernel(const float* __restrict__ y,
    const float* __restrict__ qq, float* __restrict__ dpart, float* __restrict__ wpart){
  const int PAarr[6]={0,0,1,0,1,2}, PBarr[6]={0,1,1,2,2,2};
  int blk = blockIdx.x;
  int bs = blk & 7, slot = blk >> 3;
  int pair, Kstart, nch;
  if (slot < 48){ pair = slot>>4; Kstart = (slot&15)<<10; nch=16; }
  else if (slot < 64){ pair = 3 + ((slot-48)>>3); Kstart = ((slot-48)&7)<<11; nch=32; }
  else { pair=5; Kstart = (slot-64)<<12; nch=64; }
  int PA = PAarr[pair], PB = PBarr[pair];
  int RA = PA<2?128:64, CB = PB<2?128:64;
  int s = bs & 1, b = bs >> 1, dil = 1+s;
  const float* yb = y + ((size_t)b*CC + s*HCC)*AREA_;
  const float* qqb = qq + (size_t)bs*HCC*AREA_;
  int lane = threadIdx.x & 63, wid = threadIdx.x >> 6;
  int rbase = (wid>>1)*64, cbase = (wid&1)*64;
  if (rbase >= RA || cbase >= CB) return;   // no barriers in kernel: safe early exit
  int uo = lane >> 5;
  int gr0 = PA*128 + rbase + (lane&31), gr1 = gr0+32;
  int gc0 = PB*128 + cbase + (lane&31), gc1 = gc0+32;
  f32x16 acc00={}, acc01={}, acc10={}, acc11={};
  for (int t=0;t<nch;++t){
    int k0 = Kstart + t*64;
    int w = k0>>7, h0 = k0&127;
#pragma unroll
    for (int st=0; st<4; ++st){
      int h0u = h0 + ((st*2+uo)<<3);
      half8 a0 = ufrag(yb,qqb,gr0,w,h0u,dil);
      half8 a1 = ufrag(yb,qqb,gr1,w,h0u,dil);
      half8 b0 = ufrag(yb,qqb,gc0,w,h0u,dil);
      half8 b1 = ufrag(yb,qqb,gc1,w,h0u,dil);
      acc00 = __builtin_amdgcn_mfma_f32_32x32x16_f16(a0,b0,acc00,0,0,0);
      acc01 = __builtin_amdgcn_mfma_f32_32x32x16_f16(a0,b1,acc01,0,0,0);
      acc10 = __builtin_amdgcn_mfma_f32_32x32x16_f16(a1,b0,acc10,0,0,0);
      acc11 = __builtin_amdgcn_mfma_f32_32x32x16_f16(a1,b1,acc11,0,0,0);
    }
  }
  int gid = bs*68 + slot;
  float* pp = (gid<256)? dpart + (size_t)gid*16384 : wpart + (size_t)(gid-256)*16384;
  int rr = 4*(lane>>5), cc = lane&31;
#pragma unroll
  for (int reg=0;reg<16;reg++){
    int ro = (reg&3) + 8*(reg>>2) + rr;
    pp[(size_t)(rbase+ro)*128 + cbase+cc]       = acc00[reg];
    pp[(size_t)(rbase+ro)*128 + cbase+32+cc]    = acc01[reg];
    pp[(size_t)(rbase+32+ro)*128 + cbase+cc]    = acc10[reg];
    pp[(size_t)(rbase+32+ro)*128 + cbase+32+cc] = acc11[reg];
  }
}

// ---------- reduce partials -> P (both triangles), parallel ----------
__global__ __launch_bounds__(256) void reduce_kernel(const float* __restrict__ dpart,
    const float* __restrict__ wpart, float* __restrict__ P){
  const int PAarr[6]={0,0,1,0,1,2}, PBarr[6]={0,1,1,2,2,2};
  const int slotbase[6]={0,16,32,48,56,64}, nkarr[6]={16,16,16,8,8,4};
  const int chunkbase[7]={0,16,32,48,56,64,68};
  int chunk = blockIdx.x, bs = blockIdx.y;
  int pair = 0;
  while (chunk >= chunkbase[pair+1]) pair++;
  int lc = chunk - chunkbase[pair];
  int PA = PAarr[pair], PB = PBarr[pair];
  int CN = PB<2?128:64;
  int Roff = PA*128, Coff = PB*128;
  int nk = nkarr[pair], sb0 = slotbase[pair];
  int csh = (CN==128)?7:6;
  int cell0 = lc*1024 + threadIdx.x*4;
  int r = cell0 >> csh, c = cell0 & (CN-1);
  float4 v = make_float4(0.f,0.f,0.f,0.f);
  int gidb = bs*68 + sb0;
  for (int k=0;k<nk;k++){
    int gid = gidb + k;
    const float* pp = (gid<256)? dpart + (size_t)gid*16384 : wpart + (size_t)(gid-256)*16384;
    float4 t = *(const float4*)&pp[(size_t)r*128 + c];
    v.x += t.x; v.y += t.y; v.z += t.z; v.w += t.w;
  }
  float* Pb = P + (size_t)bs*102400;
  *(float4*)&Pb[(size_t)(Roff+r)*320 + Coff+c] = v;
  Pb[(size_t)(Coff+c  )*320 + Roff+r] = v.x;
  Pb[(size_t)(Coff+c+1)*320 + Roff+r] = v.y;
  Pb[(size_t)(Coff+c+2)*320 + Roff+r] = v.z;
  Pb[(size_t)(Coff+c+3)*320 + Roff+r] = v.w;
}

// ---------- kw transpose ----------
__global__ __launch_bounds__(256) void kwT_kernel(const float* __restrict__ kw, float* __restrict__ kwT){
  int idx = blockIdx.x*256 + threadIdx.x;
  if (idx >= 2*KDIM*KDIM) return;
  int s = idx / (KDIM*KDIM);
  int r = idx - s*KDIM*KDIM;
  int k = r / KDIM, j = r - k*KDIM;
  kwT[(size_t)s*KDIM*KDIM + (size_t)j*KDIM + k] = kw[idx];
}

// ---------- fused V row + key-norm accumulation: kn[bs][k] += kw[k][j] * V[j][k] ----------
__global__ __launch_bounds__(256) void vknorm_kernel(const float* __restrict__ P,
    const float* __restrict__ kwT, float* __restrict__ kn){
  int j = blockIdx.x, bs = blockIdx.y;
  int s = bs & 1;
  __shared__ float prow[KDIM];
  const float* Pb = P + (size_t)bs*102400 + (size_t)j*320;
  for (int i=threadIdx.x;i<KDIM;i+=256) prow[i]=Pb[i];
  __syncthreads();
  const float* kt = kwT + (size_t)s*KDIM*KDIM;
  int k = threadIdx.x;
  float acc=0.f;
  for (int jp=0;jp<KDIM;jp++) acc = fmaf(prow[jp], kt[(size_t)jp*KDIM + k], acc);
  atomicAdd(&kn[bs*256 + k], kt[(size_t)j*KDIM + k] * acc);
}

// ---------- w row + inorm partial stats (norms folded in) ----------
__global__ __launch_bounds__(256) void wmat_kernel(const float* __restrict__ P,
    const float* __restrict__ kwT, const float* __restrict__ kn,
    float* __restrict__ wbuf, float* __restrict__ wstats){
  int bs = blockIdx.x >> 5, c = blockIdx.x & 31;
  int s = bs & 1;
  __shared__ float prow[KDIM];
  const float* PbB = P + (size_t)bs*102400;
  const float* Pb = PbB + (size_t)(288+c)*320;
  for (int i=threadIdx.x;i<KDIM;i+=256) prow[i]=Pb[i];
  __syncthreads();
  const float* kt = kwT + (size_t)s*KDIM*KDIM;
  int k = threadIdx.x;
  float acc=0.f;
  for (int j=0;j<KDIM;j++) acc = fmaf(prow[j], kt[(size_t)j*KDIM + k], acc);
  float rk = 1.f/fmaxf(sqrtf(fmaxf(kn[bs*256+k],0.f)),1e-12f);
  float qn = PbB[(size_t)(288+c)*320 + 288+c];
  float rq = 1.f/fmaxf(sqrtf(fmaxf(qn,0.f)),1e-12f);
  float wv = acc * rq * rk * (1.f/128.f);
  wbuf[((size_t)bs*32 + c)*256 + k] = wv;
  __shared__ float red[8];
  float r1 = warp_rsum(wv), r2 = warp_rsum(wv*wv);
  int lane = threadIdx.x & 63, wid = threadIdx.x >> 6;
  if (lane==0){ red[wid]=r1; red[4+wid]=r2; }
  __syncthreads();
  if (threadIdx.x==0){
    atomicAdd(&wstats[bs*2],   red[0]+red[1]+red[2]+red[3]);
    atomicAdd(&wstats[bs*2+1], red[4]+red[5]+red[6]+red[7]);
  }
}

// ---------- inorm + softmax ----------
__global__ __launch_bounds__(256) void smx_kernel(const float* __restrict__ wbuf,
    const float* __restrict__ wstats, float* __restrict__ sw){
  int bs = blockIdx.x >> 5, c = blockIdx.x & 31;
  float s1 = wstats[bs*2], s2 = wstats[bs*2+1];
  const float N = 8192.f;
  float m = s1/N, var = s2/N - m*m;
  float rs = rsqrtf(var + 1e-5f);
  int k = threadIdx.x;
  float v = (wbuf[((size_t)bs*32 + c)*256 + k] - m)*rs;
  __shared__ float red[4];
  float mx = warp_rmax(v);
  int lane = k & 63, wid = k >> 6;
  if (lane==0) red[wid]=mx;
  __syncthreads();
  float MX = fmaxf(fmaxf(red[0],red[1]),fmaxf(red[2],red[3]));
  __syncthreads();
  float e = expf(v - MX);
  float es = warp_rsum(e);
  if (lane==0) red[wid]=es;
  __syncthreads();
  float ES = red[0]+red[1]+red[2]+red[3];
  sw[((size_t)bs*32 + c)*256 + k] = e/ES;
}

// ---------- tap coefficients ----------
__global__ __launch_bounds__(256) void tsw_kernel(const float* __restrict__ sw, float* __restrict__ tsw){
  int idx = blockIdx.x*256 + threadIdx.x;
  if (idx >= BB*SS*32*9*32) return;
  int ch = idx & 31;
  int t = (idx >> 5) % 9;
  int c = (idx / 288) & 31;
  int bs = idx / 9216;
  const float* swb = sw + ((size_t)bs*32 + c)*256;
  float v;
  if (t==0){ v=0.f; for (int l=0;l<8;l++) v += swb[l*32+ch]; }
  else v = -swb[(t-1)*32 + ch];
  tsw[idx] = v;
}

// ---------- attention as 9-tap stencil ----------
__global__ __launch_bounds__(256) void attn_apply_kernel(const float* __restrict__ y,
    const float* __restrict__ tsw, float* __restrict__ outs){
  int blk = blockIdx.x;
  int w = blk & 127;
  int s = (blk >> 7) & 1;
  int b = blk >> 8;
  int dil = 1 + s;
  __shared__ float T[9216];
  const float* tb = tsw + (size_t)(b*SS+s)*9216;
  for (int i=threadIdx.x;i<9216;i+=256) T[i]=tb[i];
  __syncthreads();
  int h = threadIdx.x & 127, cg = threadIdx.x >> 7;
  const float* yb = y + ((size_t)b*CC + s*HCC)*AREA_;
  float acc[16];
#pragma unroll
  for (int i=0;i<16;i++) acc[i]=0.f;
  const int offy[9]={0,-1,-1,-1,0,1,1,1,0};
  const int offx[9]={0,-1,0,1,1,1,0,-1,-1};
#pragma unroll
  for (int t=0;t<9;t++){
    int wy = w + offy[t]*dil;
    if (wy < 0 || wy >= 128) continue;
    int hx = h + offx[t]*dil;
    bool okh = (hx>=0 && hx<128);
    const float* ycol = yb + (size_t)wy*128 + hx;
    for (int c4=0;c4<8;c4++){
      float v0 = okh ? ycol[(size_t)(c4*4+0)*AREA_] : 0.f;
      float v1 = okh ? ycol[(size_t)(c4*4+1)*AREA_] : 0.f;
      float v2 = okh ? ycol[(size_t)(c4*4+2)*AREA_] : 0.f;
      float v3 = okh ? ycol[(size_t)(c4*4+3)*AREA_] : 0.f;
      const float* Tp = &T[(cg*16)*288 + t*32 + c4*4];
#pragma unroll
      for (int i=0;i<16;i++){
        float4 tw = *(const float4*)&Tp[(size_t)i*288];
        acc[i] = fmaf(tw.x, v0, fmaf(tw.y, v1, fmaf(tw.z, v2, fmaf(tw.w, v3, acc[i]))));
      }
    }
  }
  float* ob = outs + ((size_t)(b*SS+s)*HCC + cg*16)*AREA_ + (size_t)w*128 + h;
#pragma unroll
  for (int i=0;i<16;i++) ob[(size_t)i*AREA_] = acc[i];
}

extern "C" void kernel_launch(void* const* d_in, const int* in_sizes, int n_in,
                              void* d_out, int out_size, void* d_ws, size_t ws_size,
                              hipStream_t stream){
  const float* x   = (const float*)d_in[0];
  const float* tw  = (const float*)d_in[1];
  const float* g1  = (const float*)d_in[2];
  const float* b1  = (const float*)d_in[3];
  const float* qw  = (const float*)d_in[4];
  const float* kw  = (const float*)d_in[5];
  const float* ow  = (const float*)d_in[6];
  const float* g2  = (const float*)d_in[7];
  const float* b2  = (const float*)d_in[8];
  float* out = (float*)d_out;
  float* ws = (float*)d_ws;

  // Workspace (floats; live ranges disjoint):
  //   [0,64) pad | y@64 | qqb@4194368 (kwT/wbuf alias after gram)
  //   wpart@8388672 (outs alias after reduce) | P@13107264
  //   stats@13926464(256) wstats@13926720(256 slot) kn@13926976(2048)  <- one memset
  //   sb@13929024(256) swb@13929280(65536) tswb@13994816(73728)  end 14068544
  // d_out: dpart (256 gram partial slots), dead before final BN write.
  float* y      = ws + 64;
  float* qqb    = ws + 4194368;
  float* kwT    = qqb;
  float* wbuf   = ws + 4360256;
  float* wpart  = ws + 8388672;
  float* outs   = wpart;
  float* P      = ws + 13107264;
  float* stats  = ws + 13926464;
  float* wstats = ws + 13926720;
  float* kn     = ws + 13926976;
  float* sb     = ws + 13929024;
  float* swb    = ws + 13929280;
  float* tswb   = ws + 13994816;
  float* dpart  = (float*)d_out;
  float* z      = y;

  hipMemsetAsync(stats, 0, 2560*sizeof(float), stream);

  conv64_kernel<<<512,256,0,stream>>>(x, tw, y);
  bn_part_kernel<<<dim3(64,8),256,0,stream>>>(y, stats);
  bn_fin_kernel<<<1,64,0,stream>>>(stats, g1, b1, sb);
  bn_apply_relu_kernel<<<16384,256,0,stream>>>(y, sb, y);
  qq_kernel<<<1024,256,0,stream>>>(y, qw, qqb);
  gram_kernel<<<544,256,0,stream>>>(y, qqb, dpart, wpart);
  reduce_kernel<<<dim3(68,8),256,0,stream>>>(dpart, wpart, P);
  kwT_kernel<<<648,256,0,stream>>>(kw, kwT);
  vknorm_kernel<<<dim3(288,8),256,0,stream>>>(P, kwT, kn);
  wmat_kernel<<<256,256,0,stream>>>(P, kwT, kn, wbuf, wstats);
  smx_kernel<<<256,256,0,stream>>>(wbuf, wstats, swb);
  tsw_kernel<<<288,256,0,stream>>>(swb, tswb);
  attn_apply_kernel<<<1024,256,0,stream>>>(y, tswb, outs);
  conv64_kernel<<<512,256,0,stream>>>(outs, ow, z);
  bn_part_kernel<<<dim3(64,8),256,0,stream>>>(z, stats+128);
  bn_fin_kernel<<<1,64,0,stream>>>(stats+128, g2, b2, sb+128);
  bn_apply_relu_kernel<<<16384,256,0,stream>>>(z, sb+128, out);
}

// Round 7
// 377.511 us; speedup vs baseline: 1.6470x; 1.6470x over previous
//
#include <hip/hip_runtime.h>

#define BB 4
#define CC 64
#define SS 2
#define HCC 32
#define AREA_ 16384
#define KDIM 288

typedef _Float16 half8 __attribute__((ext_vector_type(8)));
typedef float f32x16 __attribute__((ext_vector_type(16)));

static __device__ __forceinline__ float warp_rsum(float v){
#pragma unroll
  for (int o=32;o>0;o>>=1) v += __shfl_down(v,o,64);
  return v;
}
static __device__ __forceinline__ float warp_rmax(float v){
#pragma unroll
  for (int o=32;o>0;o>>=1) v = fmaxf(v,__shfl_down(v,o,64));
  return v;
}

// ---------- 64x64 1x1 conv ----------
__global__ __launch_bounds__(256) void conv64_kernel(const float* __restrict__ in,
    const float* __restrict__ wmat, float* __restrict__ out){
  int b = blockIdx.x >> 7;
  int p0 = (blockIdx.x & 127) << 7;
  __shared__ float tile[64][132];
  __shared__ float wsm[64][68];
  for (int idx = threadIdx.x; idx < 4096; idx += 256){
    int c = idx & 63, o = idx >> 6;
    wsm[c][o] = wmat[o*64 + c];
  }
  const float* inb = in + (size_t)b*CC*AREA_ + p0;
  for (int idx = threadIdx.x; idx < 8192; idx += 256){
    int c = idx >> 7, pp = idx & 127;
    tile[c][pp] = inb[(size_t)c*AREA_ + pp];
  }
  __syncthreads();
  int px = (threadIdx.x & 31) * 4;
  int og = threadIdx.x >> 5;
  float4 acc[8];
#pragma unroll
  for (int i=0;i<8;i++) acc[i] = make_float4(0.f,0.f,0.f,0.f);
  for (int c=0;c<64;c++){
    float4 v  = *(const float4*)&tile[c][px];
    float4 w0 = *(const float4*)&wsm[c][og*8];
    float4 w1 = *(const float4*)&wsm[c][og*8+4];
    float wv[8] = {w0.x,w0.y,w0.z,w0.w,w1.x,w1.y,w1.z,w1.w};
#pragma unroll
    for (int i=0;i<8;i++){
      acc[i].x = fmaf(wv[i], v.x, acc[i].x);
      acc[i].y = fmaf(wv[i], v.y, acc[i].y);
      acc[i].z = fmaf(wv[i], v.z, acc[i].z);
      acc[i].w = fmaf(wv[i], v.w, acc[i].w);
    }
  }
  float* ob = out + (size_t)b*CC*AREA_ + p0 + px;
#pragma unroll
  for (int i=0;i<8;i++)
    *(float4*)&ob[(size_t)(og*8+i)*AREA_] = acc[i];
}

// ---------- BN ----------
__global__ __launch_bounds__(256) void bn_part_kernel(const float* __restrict__ src,
    float* __restrict__ part){
  int c = blockIdx.x, chunk = blockIdx.y;
  float s1=0.f, s2=0.f;
  for (int b=0;b<BB;b++){
    const float* p = src + ((size_t)b*CC + c)*AREA_ + chunk*2048;
    for (int i=threadIdx.x;i<2048;i+=256){ float v=p[i]; s1+=v; s2+=v*v; }
  }
  __shared__ float red[8];
  float w1 = warp_rsum(s1), w2 = warp_rsum(s2);
  int lane = threadIdx.x & 63, wid = threadIdx.x >> 6;
  if (lane==0){ red[wid]=w1; red[4+wid]=w2; }
  __syncthreads();
  if (threadIdx.x==0){
    atomicAdd(&part[c], red[0]+red[1]+red[2]+red[3]);
    atomicAdd(&part[64+c], red[4]+red[5]+red[6]+red[7]);
  }
}

__global__ void bn_fin_kernel(const float* __restrict__ part, const float* __restrict__ gam,
    const float* __restrict__ bet, float* __restrict__ sb){
  int c = threadIdx.x;
  const float N = (float)(BB*AREA_);
  float m = part[c]/N;
  float var = part[64+c]/N - m*m;
  float sc = gam[c]*rsqrtf(var + 1e-5f);
  sb[c] = sc;
  sb[64+c] = bet[c] - m*sc;
}

__global__ __launch_bounds__(256) void bn_apply_relu_kernel(const float* __restrict__ src,
    const float* __restrict__ sb, float* __restrict__ dst){
  size_t i = (size_t)blockIdx.x*256 + threadIdx.x;
  int c = (int)((i >> 14) & 63);
  float v = fmaf(src[i], sb[c], sb[64+c]);
  dst[i] = v > 0.f ? v : 0.f;
}

// ---------- query conv ----------
__global__ __launch_bounds__(256) void qq_kernel(const float* __restrict__ y,
    const float* __restrict__ qw, float* __restrict__ qq){
  int blk = blockIdx.x;
  int p0 = (blk & 127) << 7;
  int s = (blk >> 7) & 1;
  int b = blk >> 8;
  __shared__ float tile[32][132];
  __shared__ float wsm[32][36];
  const float* qws = qw + s*HCC*HCC;
  for (int idx=threadIdx.x; idx<1024; idx+=256){
    int c = idx & 31, o = idx >> 5;
    wsm[c][o] = qws[o*32 + c];
  }
  const float* yb = y + ((size_t)b*CC + s*HCC)*AREA_ + p0;
  for (int idx=threadIdx.x; idx<4096; idx+=256){
    int c=idx>>7, pp=idx&127;
    tile[c][pp] = yb[(size_t)c*AREA_ + pp];
  }
  __syncthreads();
  int px = (threadIdx.x & 31) * 4;
  int og = threadIdx.x >> 5;
  float4 acc[4];
#pragma unroll
  for (int i=0;i<4;i++) acc[i] = make_float4(0.f,0.f,0.f,0.f);
  for (int c=0;c<32;c++){
    float4 v  = *(const float4*)&tile[c][px];
    float4 w0 = *(const float4*)&wsm[c][og*4];
    float wv[4] = {w0.x,w0.y,w0.z,w0.w};
#pragma unroll
    for (int i=0;i<4;i++){
      acc[i].x = fmaf(wv[i], v.x, acc[i].x);
      acc[i].y = fmaf(wv[i], v.y, acc[i].y);
      acc[i].z = fmaf(wv[i], v.z, acc[i].z);
      acc[i].w = fmaf(wv[i], v.w, acc[i].w);
    }
  }
  float* ob = qq + ((size_t)(b*SS+s)*HCC)*AREA_ + p0 + px;
#pragma unroll
  for (int i=0;i<4;i++)
    *(float4*)&ob[(size_t)(og*4+i)*AREA_] = acc[i];
}

// ---------- MFMA gram, LDS-staged with COALESCED staging ----------
// Staging thread map: tid = (row-within-pass)*8 + hq; 8 threads cover one U row's
// 64-col chunk (32B fp32 each) -> a wave reads 8 rows x 256B contiguous.
__global__ __launch_bounds__(256,3) void gram_kernel(const float* __restrict__ y,
    const float* __restrict__ qq, float* __restrict__ dpart, float* __restrict__ wpart){
  const int PAarr[6]={0,0,1,0,1,2}, PBarr[6]={0,1,1,2,2,2};
  int slot = 67 - blockIdx.x;        // heavy (long-K) slots dispatch first
  int bs = blockIdx.y;
  int pair, Kstart, nch;
  if (slot < 48){ pair = slot>>4; Kstart = (slot&15)<<10; nch=16; }
  else if (slot < 64){ pair = 3 + ((slot-48)>>3); Kstart = ((slot-48)&7)<<11; nch=32; }
  else { pair=5; Kstart = (slot-64)<<12; nch=64; }
  int PA = PAarr[pair], PB = PBarr[pair];
  int RA = PA<2?128:64, CB = PB<2?128:64;
  bool diag = (PA==PB);
  int rows_tot = RA + (diag?0:CB);
  int passes = rows_tot >> 5;
  int s = bs & 1, b = bs >> 1, dil = 1+s;
  const float* yb = y + ((size_t)b*CC + s*HCC)*AREA_;
  const float* qqb = qq + (size_t)bs*HCC*AREA_;
  __shared__ __align__(16) _Float16 Us[256*64];   // A rows [0,RA), B rows [RA,RA+CB)
  int tid = threadIdx.x;
  int hq = tid & 7, rr8 = tid >> 3;
  int lane = tid & 63, wid = tid >> 6;
  int rbase = (wid>>1)*64, cbase = (wid&1)*64;
  bool active = (rbase < RA) && (cbase < CB);
  int boff = diag ? 0 : RA;
  int r0 = rbase + (lane&31), r1 = r0+32;
  int cr0 = boff + cbase + (lane&31), cr1 = cr0+32;
  int uo = lane>>5;
  f32x16 acc00={}, acc01={}, acc10={}, acc11={};
  for (int t=0; t<nch; ++t){
    int k0 = Kstart + t*64;
    int w = k0>>7, h = (k0&127) + hq*8;
    for (int p=0; p<passes; ++p){
      int pr = p*32 + rr8;
      int pan, prow;
      if (pr < RA){ pan = PA; prow = pr; } else { pan = PB; prow = pr - RA; }
      float v[8];
      if (pan < 2){
        int l = pan*4 + (prow>>5), ch = prow & 31;
        int oy = ((0x6A40 >> (2*l)) & 3) - 1;
        int ox = ((0x6A4  >> (2*l)) & 3) - 1;
        const float* crow = yb + (size_t)ch*AREA_ + w*128 + h;
        float4 ca = *(const float4*)crow;
        float4 cb = *(const float4*)(crow+4);
        float cen[8] = {ca.x,ca.y,ca.z,ca.w,cb.x,cb.y,cb.z,cb.w};
        float nb[8];
        int wy = w + oy*dil, oxd = ox*dil, hb = h + oxd;
        if (wy>=0 && wy<128){
          const float* nrow = yb + (size_t)ch*AREA_ + wy*128 + hb;
          if (hb>=0 && hb<=120){
            float4 na, nc;
            __builtin_memcpy(&na, nrow, 16);
            __builtin_memcpy(&nc, nrow+4, 16);
            nb[0]=na.x; nb[1]=na.y; nb[2]=na.z; nb[3]=na.w;
            nb[4]=nc.x; nb[5]=nc.y; nb[6]=nc.z; nb[7]=nc.w;
          } else {
#pragma unroll
            for (int j=0;j<8;j++){
              int hx = hb + j;
              nb[j] = (hx>=0 && hx<128) ? nrow[j] : 0.f;
            }
          }
        } else {
#pragma unroll
          for (int j=0;j<8;j++) nb[j]=0.f;
        }
#pragma unroll
        for (int j=0;j<8;j++) v[j] = cen[j]-nb[j];
      } else {
        const float* src = (prow<32) ? yb + (size_t)prow*AREA_ : qqb + (size_t)(prow-32)*AREA_;
        const float* crow = src + w*128 + h;
        float4 ca = *(const float4*)crow;
        float4 cb = *(const float4*)(crow+4);
        v[0]=ca.x; v[1]=ca.y; v[2]=ca.z; v[3]=ca.w;
        v[4]=cb.x; v[5]=cb.y; v[6]=cb.z; v[7]=cb.w;
      }
      half8 hv;
#pragma unroll
      for (int j=0;j<8;j++) hv[j] = (_Float16)v[j];
      *(half8*)&Us[(size_t)pr*64 + ((hq ^ (pr&7))<<3)] = hv;
    }
    __syncthreads();
    if (active){
#pragma unroll
      for (int st=0; st<4; ++st){
        int u = st*2 + uo;
        half8 a0 = *(const half8*)&Us[(size_t)r0*64  + ((u^(r0&7))<<3)];
        half8 a1 = *(const half8*)&Us[(size_t)r1*64  + ((u^(r1&7))<<3)];
        half8 b0 = *(const half8*)&Us[(size_t)cr0*64 + ((u^(cr0&7))<<3)];
        half8 b1 = *(const half8*)&Us[(size_t)cr1*64 + ((u^(cr1&7))<<3)];
        acc00 = __builtin_amdgcn_mfma_f32_32x32x16_f16(a0,b0,acc00,0,0,0);
        acc01 = __builtin_amdgcn_mfma_f32_32x32x16_f16(a0,b1,acc01,0,0,0);
        acc10 = __builtin_amdgcn_mfma_f32_32x32x16_f16(a1,b0,acc10,0,0,0);
        acc11 = __builtin_amdgcn_mfma_f32_32x32x16_f16(a1,b1,acc11,0,0,0);
      }
    }
    __syncthreads();
  }
  if (active){
    int gid = bs*68 + slot;
    float* pp = (gid<256)? dpart + (size_t)gid*16384 : wpart + (size_t)(gid-256)*16384;
    int rr = 4*uo, cc = lane&31;
#pragma unroll
    for (int reg=0;reg<16;reg++){
      int ro = (reg&3) + 8*(reg>>2) + rr;
      pp[(size_t)(rbase+ro)*128 + cbase+cc]       = acc00[reg];
      pp[(size_t)(rbase+ro)*128 + cbase+32+cc]    = acc01[reg];
      pp[(size_t)(rbase+32+ro)*128 + cbase+cc]    = acc10[reg];
      pp[(size_t)(rbase+32+ro)*128 + cbase+32+cc] = acc11[reg];
    }
  }
}

// ---------- reduce partials -> P (both triangles), parallel ----------
__global__ __launch_bounds__(256) void reduce_kernel(const float* __restrict__ dpart,
    const float* __restrict__ wpart, float* __restrict__ P){
  const int PAarr[6]={0,0,1,0,1,2}, PBarr[6]={0,1,1,2,2,2};
  const int slotbase[6]={0,16,32,48,56,64}, nkarr[6]={16,16,16,8,8,4};
  const int chunkbase[7]={0,16,32,48,56,64,68};
  int chunk = blockIdx.x, bs = blockIdx.y;
  int pair = 0;
  while (chunk >= chunkbase[pair+1]) pair++;
  int lc = chunk - chunkbase[pair];
  int PA = PAarr[pair], PB = PBarr[pair];
  int CN = PB<2?128:64;
  int Roff = PA*128, Coff = PB*128;
  int nk = nkarr[pair], sb0 = slotbase[pair];
  int csh = (CN==128)?7:6;
  int cell0 = lc*1024 + threadIdx.x*4;
  int r = cell0 >> csh, c = cell0 & (CN-1);
  float4 v = make_float4(0.f,0.f,0.f,0.f);
  int gidb = bs*68 + sb0;
  for (int k=0;k<nk;k++){
    int gid = gidb + k;
    const float* pp = (gid<256)? dpart + (size_t)gid*16384 : wpart + (size_t)(gid-256)*16384;
    float4 t = *(const float4*)&pp[(size_t)r*128 + c];
    v.x += t.x; v.y += t.y; v.z += t.z; v.w += t.w;
  }
  float* Pb = P + (size_t)bs*102400;
  *(float4*)&Pb[(size_t)(Roff+r)*320 + Coff+c] = v;
  Pb[(size_t)(Coff+c  )*320 + Roff+r] = v.x;
  Pb[(size_t)(Coff+c+1)*320 + Roff+r] = v.y;
  Pb[(size_t)(Coff+c+2)*320 + Roff+r] = v.z;
  Pb[(size_t)(Coff+c+3)*320 + Roff+r] = v.w;
}

// ---------- kw transpose ----------
__global__ __launch_bounds__(256) void kwT_kernel(const float* __restrict__ kw, float* __restrict__ kwT){
  int idx = blockIdx.x*256 + threadIdx.x;
  if (idx >= 2*KDIM*KDIM) return;
  int s = idx / (KDIM*KDIM);
  int r = idx - s*KDIM*KDIM;
  int k = r / KDIM, j = r - k*KDIM;
  kwT[(size_t)s*KDIM*KDIM + (size_t)j*KDIM + k] = kw[idx];
}

// ---------- fused V row + key-norm accumulation ----------
__global__ __launch_bounds__(256) void vknorm_kernel(const float* __restrict__ P,
    const float* __restrict__ kwT, float* __restrict__ kn){
  int j = blockIdx.x, bs = blockIdx.y;
  int s = bs & 1;
  __shared__ float prow[KDIM];
  const float* Pb = P + (size_t)bs*102400 + (size_t)j*320;
  for (int i=threadIdx.x;i<KDIM;i+=256) prow[i]=Pb[i];
  __syncthreads();
  const float* kt = kwT + (size_t)s*KDIM*KDIM;
  int k = threadIdx.x;
  float acc=0.f;
  for (int jp=0;jp<KDIM;jp++) acc = fmaf(prow[jp], kt[(size_t)jp*KDIM + k], acc);
  atomicAdd(&kn[bs*256 + k], kt[(size_t)j*KDIM + k] * acc);
}

// ---------- w row + inorm partial stats (norms folded in) ----------
__global__ __launch_bounds__(256) void wmat_kernel(const float* __restrict__ P,
    const float* __restrict__ kwT, const float* __restrict__ kn,
    float* __restrict__ wbuf, float* __restrict__ wstats){
  int bs = blockIdx.x >> 5, c = blockIdx.x & 31;
  int s = bs & 1;
  __shared__ float prow[KDIM];
  const float* PbB = P + (size_t)bs*102400;
  const float* Pb = PbB + (size_t)(288+c)*320;
  for (int i=threadIdx.x;i<KDIM;i+=256) prow[i]=Pb[i];
  __syncthreads();
  const float* kt = kwT + (size_t)s*KDIM*KDIM;
  int k = threadIdx.x;
  float acc=0.f;
  for (int j=0;j<KDIM;j++) acc = fmaf(prow[j], kt[(size_t)j*KDIM + k], acc);
  float rk = 1.f/fmaxf(sqrtf(fmaxf(kn[bs*256+k],0.f)),1e-12f);
  float qn = PbB[(size_t)(288+c)*320 + 288+c];
  float rq = 1.f/fmaxf(sqrtf(fmaxf(qn,0.f)),1e-12f);
  float wv = acc * rq * rk * (1.f/128.f);
  wbuf[((size_t)bs*32 + c)*256 + k] = wv;
  __shared__ float red[8];
  float r1 = warp_rsum(wv), r2 = warp_rsum(wv*wv);
  int lane = threadIdx.x & 63, wid = threadIdx.x >> 6;
  if (lane==0){ red[wid]=r1; red[4+wid]=r2; }
  __syncthreads();
  if (threadIdx.x==0){
    atomicAdd(&wstats[bs*2],   red[0]+red[1]+red[2]+red[3]);
    atomicAdd(&wstats[bs*2+1], red[4]+red[5]+red[6]+red[7]);
  }
}

// ---------- inorm + softmax ----------
__global__ __launch_bounds__(256) void smx_kernel(const float* __restrict__ wbuf,
    const float* __restrict__ wstats, float* __restrict__ sw){
  int bs = blockIdx.x >> 5, c = blockIdx.x & 31;
  float s1 = wstats[bs*2], s2 = wstats[bs*2+1];
  const float N = 8192.f;
  float m = s1/N, var = s2/N - m*m;
  float rs = rsqrtf(var + 1e-5f);
  int k = threadIdx.x;
  float v = (wbuf[((size_t)bs*32 + c)*256 + k] - m)*rs;
  __shared__ float red[4];
  float mx = warp_rmax(v);
  int lane = k & 63, wid = k >> 6;
  if (lane==0) red[wid]=mx;
  __syncthreads();
  float MX = fmaxf(fmaxf(red[0],red[1]),fmaxf(red[2],red[3]));
  __syncthreads();
  float e = expf(v - MX);
  float es = warp_rsum(e);
  if (lane==0) red[wid]=es;
  __syncthreads();
  float ES = red[0]+red[1]+red[2]+red[3];
  sw[((size_t)bs*32 + c)*256 + k] = e/ES;
}

// ---------- tap coefficients ----------
__global__ __launch_bounds__(256) void tsw_kernel(const float* __restrict__ sw, float* __restrict__ tsw){
  int idx = blockIdx.x*256 + threadIdx.x;
  if (idx >= BB*SS*32*9*32) return;
  int ch = idx & 31;
  int t = (idx >> 5) % 9;
  int c = (idx / 288) & 31;
  int bs = idx / 9216;
  const float* swb = sw + ((size_t)bs*32 + c)*256;
  float v;
  if (t==0){ v=0.f; for (int l=0;l<8;l++) v += swb[l*32+ch]; }
  else v = -swb[(t-1)*32 + ch];
  tsw[idx] = v;
}

// ---------- attention as 9-tap stencil ----------
__global__ __launch_bounds__(256) void attn_apply_kernel(const float* __restrict__ y,
    const float* __restrict__ tsw, float* __restrict__ outs){
  int blk = blockIdx.x;
  int w = blk & 127;
  int s = (blk >> 7) & 1;
  int b = blk >> 8;
  int dil = 1 + s;
  __shared__ float T[9216];
  const float* tb = tsw + (size_t)(b*SS+s)*9216;
  for (int i=threadIdx.x;i<9216;i+=256) T[i]=tb[i];
  __syncthreads();
  int h = threadIdx.x & 127, cg = threadIdx.x >> 7;
  const float* yb = y + ((size_t)b*CC + s*HCC)*AREA_;
  float acc[16];
#pragma unroll
  for (int i=0;i<16;i++) acc[i]=0.f;
  const int offy[9]={0,-1,-1,-1,0,1,1,1,0};
  const int offx[9]={0,-1,0,1,1,1,0,-1,-1};
#pragma unroll
  for (int t=0;t<9;t++){
    int wy = w + offy[t]*dil;
    if (wy < 0 || wy >= 128) continue;
    int hx = h + offx[t]*dil;
    bool okh = (hx>=0 && hx<128);
    const float* ycol = yb + (size_t)wy*128 + hx;
    for (int c4=0;c4<8;c4++){
      float v0 = okh ? ycol[(size_t)(c4*4+0)*AREA_] : 0.f;
      float v1 = okh ? ycol[(size_t)(c4*4+1)*AREA_] : 0.f;
      float v2 = okh ? ycol[(size_t)(c4*4+2)*AREA_] : 0.f;
      float v3 = okh ? ycol[(size_t)(c4*4+3)*AREA_] : 0.f;
      const float* Tp = &T[(cg*16)*288 + t*32 + c4*4];
#pragma unroll
      for (int i=0;i<16;i++){
        float4 tw = *(const float4*)&Tp[(size_t)i*288];
        acc[i] = fmaf(tw.x, v0, fmaf(tw.y, v1, fmaf(tw.z, v2, fmaf(tw.w, v3, acc[i]))));
      }
    }
  }
  float* ob = outs + ((size_t)(b*SS+s)*HCC + cg*16)*AREA_ + (size_t)w*128 + h;
#pragma unroll
  for (int i=0;i<16;i++) ob[(size_t)i*AREA_] = acc[i];
}

extern "C" void kernel_launch(void* const* d_in, const int* in_sizes, int n_in,
                              void* d_out, int out_size, void* d_ws, size_t ws_size,
                              hipStream_t stream){
  const float* x   = (const float*)d_in[0];
  const float* tw  = (const float*)d_in[1];
  const float* g1  = (const float*)d_in[2];
  const float* b1  = (const float*)d_in[3];
  const float* qw  = (const float*)d_in[4];
  const float* kw  = (const float*)d_in[5];
  const float* ow  = (const float*)d_in[6];
  const float* g2  = (const float*)d_in[7];
  const float* b2  = (const float*)d_in[8];
  float* out = (float*)d_out;
  float* ws = (float*)d_ws;

  // Workspace (floats; live ranges disjoint):
  //   [0,64) pad | y@64 | qqb@4194368 (kwT/wbuf alias after gram)
  //   wpart@8388672 (outs alias after reduce) | P@13107264
  //   stats@13926464(256) wstats@13926720(256 slot) kn@13926976(2048) <- one memset
  //   sb@13929024(256) swb@13929280(65536) tswb@13994816(73728) end 14068544
  // d_out: dpart (256 gram partial slots), dead before final BN write.
  float* y      = ws + 64;
  float* qqb    = ws + 4194368;
  float* kwT    = qqb;
  float* wbuf   = ws + 4360256;
  float* wpart  = ws + 8388672;
  float* outs   = wpart;
  float* P      = ws + 13107264;
  float* stats  = ws + 13926464;
  float* wstats = ws + 13926720;
  float* kn     = ws + 13926976;
  float* sb     = ws + 13929024;
  float* swb    = ws + 13929280;
  float* tswb   = ws + 13994816;
  float* dpart  = (float*)d_out;
  float* z      = y;

  hipMemsetAsync(stats, 0, 2560*sizeof(float), stream);

  conv64_kernel<<<512,256,0,stream>>>(x, tw, y);
  bn_part_kernel<<<dim3(64,8),256,0,stream>>>(y, stats);
  bn_fin_kernel<<<1,64,0,stream>>>(stats, g1, b1, sb);
  bn_apply_relu_kernel<<<16384,256,0,stream>>>(y, sb, y);
  qq_kernel<<<1024,256,0,stream>>>(y, qw, qqb);
  gram_kernel<<<dim3(68,8),256,0,stream>>>(y, qqb, dpart, wpart);
  reduce_kernel<<<dim3(68,8),256,0,stream>>>(dpart, wpart, P);
  kwT_kernel<<<648,256,0,stream>>>(kw, kwT);
  vknorm_kernel<<<dim3(288,8),256,0,stream>>>(P, kwT, kn);
  wmat_kernel<<<256,256,0,stream>>>(P, kwT, kn, wbuf, wstats);
  smx_kernel<<<256,256,0,stream>>>(wbuf, wstats, swb);
  tsw_kernel<<<288,256,0,stream>>>(swb, tswb);
  attn_apply_kernel<<<1024,256,0,stream>>>(y, tswb, outs);
  conv64_kernel<<<512,256,0,stream>>>(outs, ow, z);
  bn_part_kernel<<<dim3(64,8),256,0,stream>>>(z, stats+128);
  bn_fin_kernel<<<1,64,0,stream>>>(stats+128, g2, b2, sb+128);
  bn_apply_relu_kernel<<<16384,256,0,stream>>>(z, sb+128, out);
}